// Round 14
// baseline (113.572 us; speedup 1.0000x reference)
//
#include <hip/hip_runtime.h>
#include <math.h>

// DTW loss: B=128, L1=L2=512, D=16.
// R14: 2-wave column-split skewed systolic, C=4 cols/lane.
//  - y tile (4 cols x 16 dims = 64 VGPRs) pinned via VOLATILE global loads
//    (one-time; cannot be re-executed -> values stay live in registers)
//  - x rows: R13's quad-plane LDS layout + asm-volatile ds_read ring-4,
//    counted s_waitcnt lgkmcnt(10) + sched_barrier (rule #18)
//  - skew WOFF=71, EP=8 substeps/epoch, NE=81 epochs, one barrier/epoch
//  - wave0 -> wave1 boundary via 8-row LDS packets (R11-verified logic)
// Floors addressed: LDS pipe traffic halved (2 waves), y-remat eliminated.

#define TL 512
#define TD 16
#define TNB 128
#define BIGF 3.0e38f
#define INFF __builtin_inff()
#define WOFF 71
#define EP 8
#define NE 81      // last substep needed: 511 + (71+63) = 645; 81*8 = 648

typedef float f32x2 __attribute__((ext_vector_type(2)));
typedef float f32x4 __attribute__((ext_vector_type(4)));

__device__ inline f32x2 pk_fma(f32x2 a, f32x2 b, f32x2 c) {
    f32x2 d;
    asm("v_pk_fma_f32 %0, %1, %2, %3" : "=v"(d) : "v"(a), "v"(b), "v"(c));
    return d;
}
__device__ inline f32x2 pk_mul(f32x2 a, f32x2 b) {
    f32x2 d;
    asm("v_pk_mul_f32 %0, %1, %2" : "=v"(d) : "v"(a), "v"(b));
    return d;
}
__device__ inline float min3f(float a, float b, float c) {
    float d;
    asm("v_min3_f32 %0, %1, %2, %3" : "=v"(d) : "v"(a), "v"(b), "v"(c));
    return d;
}
template<int CTRL, int RM, bool BC>
__device__ inline float dpp_mov(float old_, float src) {
    return __int_as_float(__builtin_amdgcn_update_dpp(
        __float_as_int(old_), __float_as_int(src), CTRL, RM, 0xf, BC));
}

struct XR { f32x4 q0, q1, q2, q3; float sq; };

// issue 5 DS reads for clamped row r from the quad planes (conflict-free)
__device__ inline void xissue(unsigned xb, unsigned sb, int r, XR& x) {
    int rc = r < 0 ? 0 : (r > TL - 1 ? TL - 1 : r);
    unsigned a16 = xb + ((unsigned)rc << 4);
    unsigned a4  = sb + ((unsigned)rc << 2);
    asm volatile("ds_read_b128 %0, %1 offset:0"     : "=v"(x.q0) : "v"(a16));
    asm volatile("ds_read_b128 %0, %1 offset:8192"  : "=v"(x.q1) : "v"(a16));
    asm volatile("ds_read_b128 %0, %1 offset:16384" : "=v"(x.q2) : "v"(a16));
    asm volatile("ds_read_b128 %0, %1 offset:24576" : "=v"(x.q3) : "v"(a16));
    asm volatile("ds_read_b32  %0, %1 offset:0"     : "=v"(x.sq) : "v"(a4));
}

#define WAITC() { asm volatile("s_waitcnt lgkmcnt(10)" ::: "memory"); \
                  __builtin_amdgcn_sched_barrier(0); }

// one substep: 4 cells (cols j0..j0+3) of row r
__device__ inline void sub(const XR& x, int r,
                           const f32x2 (&y0)[8], const f32x2 (&y1)[8],
                           const f32x2 (&y2)[8], const f32x2 (&y3)[8],
                           f32x2 ys0, f32x2 ys1, f32x2 ys2, f32x2 ys3,
                           float& pv0, float& pv1, float& pv2, float& pv3,
                           float& o3, float bL, float bD, bool lane0) {
    const f32x2* xd = (const f32x2*)&x;          // q0..q3 as 8 f32x2
    f32x2 a0 = ys0, a1 = ys1, a2 = ys2, a3 = ys3;   // {ysq,0}; y pre-scaled -2
    #pragma unroll
    for (int k = 0; k < 8; ++k) {
        a0 = pk_fma(xd[k], y0[k], a0);
        a1 = pk_fma(xd[k], y1[k], a1);
        a2 = pk_fma(xd[k], y2[k], a2);
        a3 = pk_fma(xd[k], y3[k], a3);
    }
    const float c0 = x.sq + (a0.x + a0.y);
    const float c1 = x.sq + (a1.x + a1.y);
    const float c2 = x.sq + (a2.x + a2.y);
    const float c3 = x.sq + (a3.x + a3.y);

    float left = dpp_mov<0x138, 0xf, false>(BIGF, pv3);  // DTW[r][j0-1]
    float diag = dpp_mov<0x138, 0xf, false>(BIGF, o3);   // DTW[r-1][j0-1]
    if (lane0) { left = bL; diag = bD; }
    o3 = pv3;

    const float v0 = c0 + min3f(pv0, left, diag);
    const float v1 = c1 + min3f(pv1, v0, pv0);
    const float v2 = c2 + min3f(pv2, v1, pv1);
    const float v3 = c3 + min3f(pv3, v2, pv2);
    const bool valid = (unsigned)r < (unsigned)TL;
    pv0 = valid ? v0 : pv0;
    pv1 = valid ? v1 : pv1;
    pv2 = valid ? v2 : pv2;
    pv3 = valid ? v3 : pv3;
}

__global__ __launch_bounds__(128, 1) void dtw_split_kernel(const float* __restrict__ s1,
                                                           const float* __restrict__ s2,
                                                           float* __restrict__ ws) {
    const int b   = blockIdx.x;
    const int tid = threadIdx.x;
    const int W   = tid >> 6;    // wave 0..1
    const int l   = tid & 63;

    __shared__ f32x4 xT[4][TL];         // 32 KB quad planes (stride 8 KB)
    __shared__ float sqT[TL];           // 2 KB row sumsq
    __shared__ f32x4 pkt[2][2];         // wave0->wave1 packets (8 rows/epoch)

    const float* s1b = s1 + (size_t)b * TL * TD;

    // stage s1 rows (4/thread) into quad planes + sumsq
    #pragma unroll
    for (int q = 0; q < 4; ++q) {
        const int r = tid + 128 * q;
        const f32x4* src = (const f32x4*)(s1b + r * TD);
        f32x4 q0 = src[0], q1 = src[1], q2 = src[2], q3 = src[3];
        xT[0][r] = q0; xT[1][r] = q1; xT[2][r] = q2; xT[3][r] = q3;
        f32x2 a_ = pk_mul(f32x2{q0.x, q0.y}, f32x2{q0.x, q0.y});
        a_ = pk_fma(f32x2{q0.z, q0.w}, f32x2{q0.z, q0.w}, a_);
        a_ = pk_fma(f32x2{q1.x, q1.y}, f32x2{q1.x, q1.y}, a_);
        a_ = pk_fma(f32x2{q1.z, q1.w}, f32x2{q1.z, q1.w}, a_);
        a_ = pk_fma(f32x2{q2.x, q2.y}, f32x2{q2.x, q2.y}, a_);
        a_ = pk_fma(f32x2{q2.z, q2.w}, f32x2{q2.z, q2.w}, a_);
        a_ = pk_fma(f32x2{q3.x, q3.y}, f32x2{q3.x, q3.y}, a_);
        a_ = pk_fma(f32x2{q3.z, q3.w}, f32x2{q3.z, q3.w}, a_);
        sqT[r] = a_.x + a_.y;
    }
    if (tid < 16) ((float*)pkt)[tid] = BIGF;

    // y tile: 4 cols/lane, VOLATILE loads (pin in VGPRs); prescale -2
    const int j0 = 4 * (64 * W + l);
    const float* yp = s2 + ((size_t)b * TL + j0) * TD;
    f32x2 y0[8], y1[8], y2[8], y3[8];
    #pragma unroll
    for (int k = 0; k < 8; ++k) {
        y0[k] = *(const volatile f32x2*)(yp + 0 * TD + 2 * k);
        y1[k] = *(const volatile f32x2*)(yp + 1 * TD + 2 * k);
        y2[k] = *(const volatile f32x2*)(yp + 2 * TD + 2 * k);
        y3[k] = *(const volatile f32x2*)(yp + 3 * TD + 2 * k);
    }
    f32x2 s0a = pk_mul(y0[0], y0[0]), s1a = pk_mul(y1[0], y1[0]);
    f32x2 s2a = pk_mul(y2[0], y2[0]), s3a = pk_mul(y3[0], y3[0]);
    #pragma unroll
    for (int k = 1; k < 8; ++k) {
        s0a = pk_fma(y0[k], y0[k], s0a);
        s1a = pk_fma(y1[k], y1[k], s1a);
        s2a = pk_fma(y2[k], y2[k], s2a);
        s3a = pk_fma(y3[k], y3[k], s3a);
    }
    const f32x2 ys0 = {s0a.x + s0a.y, 0.f};
    const f32x2 ys1 = {s1a.x + s1a.y, 0.f};
    const f32x2 ys2 = {s2a.x + s2a.y, 0.f};
    const f32x2 ys3 = {s3a.x + s3a.y, 0.f};
    #pragma unroll
    for (int k = 0; k < 8; ++k) {
        y0[k] = pk_mul(y0[k], f32x2{-2.f, -2.f});
        y1[k] = pk_mul(y1[k], f32x2{-2.f, -2.f});
        y2[k] = pk_mul(y2[k], f32x2{-2.f, -2.f});
        y3[k] = pk_mul(y3[k], f32x2{-2.f, -2.f});
    }

    __syncthreads();

    const unsigned xb = (unsigned)(uintptr_t)&xT[0][0];
    const unsigned sb = (unsigned)(uintptr_t)&sqT[0];
    const int gL = WOFF * W + l;
    const bool lane0 = (l == 0);
    float pv0 = INFF, pv1 = INFF, pv2 = INFF, pv3 = INFF, o3 = INFF;
    float carry = (W == 0) ? 0.f : BIGF;   // lane0 diag seed DTW[-1][-1]=0

    XR x0, x1, x2, x3;
    xissue(xb, sb, 0 - gL, x0);
    xissue(xb, sb, 1 - gL, x1);
    xissue(xb, sb, 2 - gL, x2);

    for (int e = 0; e < NE; ++e) {
        float lb0 = BIGF, lb1 = BIGF, lb2 = BIGF, lb3 = BIGF;
        float lb4 = BIGF, lb5 = BIGF, lb6 = BIGF, lb7 = BIGF;
        if (W > 0) {
            f32x4 pA = pkt[(e + 1) & 1][0];
            f32x4 pB = pkt[(e + 1) & 1][1];
            lb0 = pA.x; lb1 = pA.y; lb2 = pA.z; lb3 = pA.w;
            lb4 = pB.x; lb5 = pB.y; lb6 = pB.z; lb7 = pB.w;
        }
        const int rb = EP * e - gL;
        float t0, t1, t2, t3, t4, t5, t6, t7;

        WAITC(); xissue(xb, sb, rb + 3,  x3);
        sub(x0, rb + 0, y0, y1, y2, y3, ys0, ys1, ys2, ys3,
            pv0, pv1, pv2, pv3, o3, lb0, carry, lane0); t0 = pv3;
        WAITC(); xissue(xb, sb, rb + 4,  x0);
        sub(x1, rb + 1, y0, y1, y2, y3, ys0, ys1, ys2, ys3,
            pv0, pv1, pv2, pv3, o3, lb1, lb0, lane0);   t1 = pv3;
        WAITC(); xissue(xb, sb, rb + 5,  x1);
        sub(x2, rb + 2, y0, y1, y2, y3, ys0, ys1, ys2, ys3,
            pv0, pv1, pv2, pv3, o3, lb2, lb1, lane0);   t2 = pv3;
        WAITC(); xissue(xb, sb, rb + 6,  x2);
        sub(x3, rb + 3, y0, y1, y2, y3, ys0, ys1, ys2, ys3,
            pv0, pv1, pv2, pv3, o3, lb3, lb2, lane0);   t3 = pv3;
        WAITC(); xissue(xb, sb, rb + 7,  x3);
        sub(x0, rb + 4, y0, y1, y2, y3, ys0, ys1, ys2, ys3,
            pv0, pv1, pv2, pv3, o3, lb4, lb3, lane0);   t4 = pv3;
        WAITC(); xissue(xb, sb, rb + 8,  x0);
        sub(x1, rb + 5, y0, y1, y2, y3, ys0, ys1, ys2, ys3,
            pv0, pv1, pv2, pv3, o3, lb5, lb4, lane0);   t5 = pv3;
        WAITC(); xissue(xb, sb, rb + 9,  x1);
        sub(x2, rb + 6, y0, y1, y2, y3, ys0, ys1, ys2, ys3,
            pv0, pv1, pv2, pv3, o3, lb6, lb5, lane0);   t6 = pv3;
        WAITC(); xissue(xb, sb, rb + 10, x2);
        sub(x3, rb + 7, y0, y1, y2, y3, ys0, ys1, ys2, ys3,
            pv0, pv1, pv2, pv3, o3, lb7, lb6, lane0);   t7 = pv3;

        carry = lb7;

        if (l == 63 && W == 0) {
            pkt[e & 1][0] = f32x4{t0, t1, t2, t3};
            pkt[e & 1][1] = f32x4{t4, t5, t6, t7};
        }
        __syncthreads();
    }

    if (W == 1 && l == 63) ws[b] = sqrtf(pv3);   // DTW[511][511]
}

__global__ void dtw_reduce_kernel(const float* __restrict__ ws, float* __restrict__ out) {
    const int t = threadIdx.x;          // 64 threads
    float v = ws[t] + ws[t + 64];
    #pragma unroll
    for (int d2 = 32; d2 > 0; d2 >>= 1) v += __shfl_down(v, d2);
    if (t == 0) out[0] = v * (1.0f / TNB);
}

extern "C" void kernel_launch(void* const* d_in, const int* in_sizes, int n_in,
                              void* d_out, int out_size, void* d_ws, size_t ws_size,
                              hipStream_t stream) {
    const float* s1 = (const float*)d_in[0];
    const float* s2 = (const float*)d_in[1];
    float* ws  = (float*)d_ws;
    float* out = (float*)d_out;

    dtw_split_kernel<<<TNB, 128, 0, stream>>>(s1, s2, ws);
    dtw_reduce_kernel<<<1, 64, 0, stream>>>(ws, out);
}

// Round 15
// 91.284 us; speedup vs baseline: 1.2442x; 1.2442x over previous
//
#include <hip/hip_runtime.h>
#include <math.h>

// DTW loss: B=128, L1=L2=512, D=16.
// R15 = R13 (4-wave column-split skewed systolic, quad-plane conflict-free
// x layout, ring-4 asm ds_read pipeline) with ONE change:
//   the counted wait is a DEPENDENCE-CARRYING asm ("+v" on the buffer regs)
//   instead of s_waitcnt + sched_barrier(0). Ordering is preserved by
//   (volatile-asm mutual order) + (data dep through the buffer), and the
//   compiler is now free to interleave substep n+1's independent FMA stream
//   into substep n's DP-chain stall slots (software pipelining).

#define TL 512
#define TD 16
#define TNB 128
#define BIGF 3.0e38f
#define INFF __builtin_inff()
#define WOFF 71
#define EP 8
#define NE 99

typedef float f32x2 __attribute__((ext_vector_type(2)));
typedef float f32x4 __attribute__((ext_vector_type(4)));

__device__ inline f32x2 pk_fma(f32x2 a, f32x2 b, f32x2 c) {
    f32x2 d;
    asm("v_pk_fma_f32 %0, %1, %2, %3" : "=v"(d) : "v"(a), "v"(b), "v"(c));
    return d;
}
__device__ inline f32x2 pk_mul(f32x2 a, f32x2 b) {
    f32x2 d;
    asm("v_pk_mul_f32 %0, %1, %2" : "=v"(d) : "v"(a), "v"(b));
    return d;
}
__device__ inline float min3f(float a, float b, float c) {
    float d;
    asm("v_min3_f32 %0, %1, %2, %3" : "=v"(d) : "v"(a), "v"(b), "v"(c));
    return d;
}
template<int CTRL, int RM, bool BC>
__device__ inline float dpp_mov(float old_, float src) {
    return __int_as_float(__builtin_amdgcn_update_dpp(
        __float_as_int(old_), __float_as_int(src), CTRL, RM, 0xf, BC));
}

struct XR { f32x4 q0, q1, q2, q3; float sq; };

// issue 5 DS reads for clamped row r from the quad planes (conflict-free)
__device__ inline void xissue(unsigned xb, unsigned sb, int r, XR& x) {
    int rc = r < 0 ? 0 : (r > TL - 1 ? TL - 1 : r);
    unsigned a16 = xb + ((unsigned)rc << 4);
    unsigned a4  = sb + ((unsigned)rc << 2);
    asm volatile("ds_read_b128 %0, %1 offset:0"     : "=v"(x.q0) : "v"(a16));
    asm volatile("ds_read_b128 %0, %1 offset:8192"  : "=v"(x.q1) : "v"(a16));
    asm volatile("ds_read_b128 %0, %1 offset:16384" : "=v"(x.q2) : "v"(a16));
    asm volatile("ds_read_b128 %0, %1 offset:24576" : "=v"(x.q3) : "v"(a16));
    asm volatile("ds_read_b32  %0, %1 offset:0"     : "=v"(x.sq) : "v"(a4));
}

// dependence-carrying counted wait: uses of x.* after this are data-dependent
// on the wait; volatile order keeps it after the matching ds_reads. No
// sched_barrier -> compiler may pipeline independent VALU across it.
#define WAITX(x) asm volatile("s_waitcnt lgkmcnt(10)" \
    : "+v"(x.q0), "+v"(x.q1), "+v"(x.q2), "+v"(x.q3), "+v"(x.sq))

__device__ inline void sub(const XR& x, int r,
                           const f32x2 (&y0)[8], const f32x2 (&y1)[8],
                           f32x2 ys0, f32x2 ys1,
                           float& pv0, float& pv1, float& o1,
                           float bL, float bD, bool lane0) {
    const f32x2* xd = (const f32x2*)&x;          // q0..q3 as 8 f32x2
    f32x2 a0 = ys0, a1 = ys1;                    // {ysq, 0}; y pre-scaled -2
    #pragma unroll
    for (int k = 0; k < 8; ++k) {
        a0 = pk_fma(xd[k], y0[k], a0);
        a1 = pk_fma(xd[k], y1[k], a1);
    }
    const float c0 = x.sq + (a0.x + a0.y);
    const float c1 = x.sq + (a1.x + a1.y);

    float left = dpp_mov<0x138, 0xf, false>(BIGF, pv1);  // DTW[r][j0-1]
    float diag = dpp_mov<0x138, 0xf, false>(BIGF, o1);   // DTW[r-1][j0-1]
    if (lane0) { left = bL; diag = bD; }
    o1 = pv1;

    const float v0 = c0 + min3f(pv0, left, diag);
    const float v1 = c1 + min3f(pv1, v0, pv0);
    const bool valid = (unsigned)r < (unsigned)TL;
    pv0 = valid ? v0 : pv0;
    pv1 = valid ? v1 : pv1;
}

__global__ __launch_bounds__(256, 1) void dtw_split_kernel(const float* __restrict__ s1,
                                                           const float* __restrict__ s2,
                                                           float* __restrict__ ws) {
    const int b   = blockIdx.x;
    const int tid = threadIdx.x;
    const int W   = tid >> 6;    // wave 0..3
    const int l   = tid & 63;

    __shared__ f32x4 xT[4][TL];         // 32 KB quad planes (stride 8 KB)
    __shared__ float sqT[TL];           // 2 KB row sumsq
    __shared__ f32x4 pkt[2][4][2];      // boundary packets (8 rows each)

    const float* s1b = s1 + (size_t)b * TL * TD;

    // stage s1 rows (2/thread) into quad planes + sumsq
    #pragma unroll
    for (int q = 0; q < 2; ++q) {
        const int r = 2 * tid + q;
        const f32x4* src = (const f32x4*)(s1b + r * TD);
        f32x4 q0 = src[0], q1 = src[1], q2 = src[2], q3 = src[3];
        xT[0][r] = q0; xT[1][r] = q1; xT[2][r] = q2; xT[3][r] = q3;
        f32x2 a_ = pk_mul(f32x2{q0.x, q0.y}, f32x2{q0.x, q0.y});
        a_ = pk_fma(f32x2{q0.z, q0.w}, f32x2{q0.z, q0.w}, a_);
        a_ = pk_fma(f32x2{q1.x, q1.y}, f32x2{q1.x, q1.y}, a_);
        a_ = pk_fma(f32x2{q1.z, q1.w}, f32x2{q1.z, q1.w}, a_);
        a_ = pk_fma(f32x2{q2.x, q2.y}, f32x2{q2.x, q2.y}, a_);
        a_ = pk_fma(f32x2{q2.z, q2.w}, f32x2{q2.z, q2.w}, a_);
        a_ = pk_fma(f32x2{q3.x, q3.y}, f32x2{q3.x, q3.y}, a_);
        a_ = pk_fma(f32x2{q3.z, q3.w}, f32x2{q3.z, q3.w}, a_);
        sqT[r] = a_.x + a_.y;
    }
    if (tid < 64) ((float*)pkt)[tid] = BIGF;

    // y tile: 2 cols/lane; prescale -2; acc seeds {ysq, 0}
    const int j0 = 2 * (64 * W + l);
    f32x2 y0[8], y1[8];
    const float* yp0 = s2 + ((size_t)b * TL + j0) * TD;
    #pragma unroll
    for (int k = 0; k < 8; ++k) {
        y0[k] = *(const f32x2*)(yp0 + 2 * k);
        y1[k] = *(const f32x2*)(yp0 + TD + 2 * k);
    }
    f32x2 s0a = pk_mul(y0[0], y0[0]), s1a = pk_mul(y1[0], y1[0]);
    #pragma unroll
    for (int k = 1; k < 8; ++k) {
        s0a = pk_fma(y0[k], y0[k], s0a);
        s1a = pk_fma(y1[k], y1[k], s1a);
    }
    const f32x2 ys0 = {s0a.x + s0a.y, 0.f};
    const f32x2 ys1 = {s1a.x + s1a.y, 0.f};
    #pragma unroll
    for (int k = 0; k < 8; ++k) {
        y0[k] = pk_mul(y0[k], f32x2{-2.f, -2.f});
        y1[k] = pk_mul(y1[k], f32x2{-2.f, -2.f});
    }

    __syncthreads();

    const unsigned xb = (unsigned)(uintptr_t)&xT[0][0];
    const unsigned sb = (unsigned)(uintptr_t)&sqT[0];
    const int gL = WOFF * W + l;
    const bool lane0 = (l == 0);
    float pv0 = INFF, pv1 = INFF, o1 = INFF;
    float carry = (W == 0) ? 0.f : BIGF;   // lane0 diag seed DTW[-1][-1]=0

    XR x0, x1, x2, x3;
    xissue(xb, sb, 0 - gL, x0);
    xissue(xb, sb, 1 - gL, x1);
    xissue(xb, sb, 2 - gL, x2);

    for (int e = 0; e < NE; ++e) {
        float lb0 = BIGF, lb1 = BIGF, lb2 = BIGF, lb3 = BIGF;
        float lb4 = BIGF, lb5 = BIGF, lb6 = BIGF, lb7 = BIGF;
        if (W > 0) {
            f32x4 pA = pkt[(e + 1) & 1][W - 1][0];
            f32x4 pB = pkt[(e + 1) & 1][W - 1][1];
            lb0 = pA.x; lb1 = pA.y; lb2 = pA.z; lb3 = pA.w;
            lb4 = pB.x; lb5 = pB.y; lb6 = pB.z; lb7 = pB.w;
        }
        const int rb = EP * e - gL;
        float t0, t1, t2, t3, t4, t5, t6, t7;

        WAITX(x0); xissue(xb, sb, rb + 3,  x3);
        sub(x0, rb + 0, y0, y1, ys0, ys1, pv0, pv1, o1, lb0, carry, lane0); t0 = pv1;
        WAITX(x1); xissue(xb, sb, rb + 4,  x0);
        sub(x1, rb + 1, y0, y1, ys0, ys1, pv0, pv1, o1, lb1, lb0, lane0);   t1 = pv1;
        WAITX(x2); xissue(xb, sb, rb + 5,  x1);
        sub(x2, rb + 2, y0, y1, ys0, ys1, pv0, pv1, o1, lb2, lb1, lane0);   t2 = pv1;
        WAITX(x3); xissue(xb, sb, rb + 6,  x2);
        sub(x3, rb + 3, y0, y1, ys0, ys1, pv0, pv1, o1, lb3, lb2, lane0);   t3 = pv1;
        WAITX(x0); xissue(xb, sb, rb + 7,  x3);
        sub(x0, rb + 4, y0, y1, ys0, ys1, pv0, pv1, o1, lb4, lb3, lane0);   t4 = pv1;
        WAITX(x1); xissue(xb, sb, rb + 8,  x0);
        sub(x1, rb + 5, y0, y1, ys0, ys1, pv0, pv1, o1, lb5, lb4, lane0);   t5 = pv1;
        WAITX(x2); xissue(xb, sb, rb + 9,  x1);
        sub(x2, rb + 6, y0, y1, ys0, ys1, pv0, pv1, o1, lb6, lb5, lane0);   t6 = pv1;
        WAITX(x3); xissue(xb, sb, rb + 10, x2);
        sub(x3, rb + 7, y0, y1, ys0, ys1, pv0, pv1, o1, lb7, lb6, lane0);   t7 = pv1;

        carry = lb7;

        if (l == 63 && W < 3) {
            pkt[e & 1][W][0] = f32x4{t0, t1, t2, t3};
            pkt[e & 1][W][1] = f32x4{t4, t5, t6, t7};
        }
        __syncthreads();
    }

    if (W == 3 && l == 63) ws[b] = sqrtf(pv1);   // DTW[511][511]
}

__global__ void dtw_reduce_kernel(const float* __restrict__ ws, float* __restrict__ out) {
    const int t = threadIdx.x;          // 64 threads
    float v = ws[t] + ws[t + 64];
    #pragma unroll
    for (int d2 = 32; d2 > 0; d2 >>= 1) v += __shfl_down(v, d2);
    if (t == 0) out[0] = v * (1.0f / TNB);
}

extern "C" void kernel_launch(void* const* d_in, const int* in_sizes, int n_in,
                              void* d_out, int out_size, void* d_ws, size_t ws_size,
                              hipStream_t stream) {
    const float* s1 = (const float*)d_in[0];
    const float* s2 = (const float*)d_in[1];
    float* ws  = (float*)d_ws;
    float* out = (float*)d_out;

    dtw_split_kernel<<<TNB, 256, 0, stream>>>(s1, s2, ws);
    dtw_reduce_kernel<<<1, 64, 0, stream>>>(ws, out);
}